// Round 1
// baseline (349.178 us; speedup 1.0000x reference)
//
#include <hip/hip_runtime.h>

// MAUCHLoss: B=2097152 rows, C=15 categories, f32 inputs.
//
// R8: main kernel was MLP-bound (4.6 TB/s): register PF pipeline caps
// in-flight bytes at waves/CU * PF * 32B ~= 5KB < ~9KB needed at ~375ns
// HBM latency. Switch staging to global_load_lds (DMA -> LDS ring,
// DEPTH=2 per wave, wave-private, no barriers) so in-flight bytes come
// from LDS not VGPRs; VGPR drops to ~40 -> __launch_bounds__(256,8),
// 1920 blocks (mult of 15 keeps category phase constant), ITERS=16,
// one residency round at ~32 waves/CU. ~96KB/CU in flight -> BW-bound.
// Also: per-block partial sums (no global atomics, no ws memset dispatch).
//
// ws layout (mode=1): ws[k*PLD + block], k in [0,46): 0..14 sum(sig),
// 15..29 sum(sig*label), 30..44 sum(label), 45 sum(softplus(-sig)).

#define CATS 15
#define NBLOCKS 1920  // 1920*256*4 = 1,966,080 = 15*131072 -> phase constant
#define NTHREADS 256
#define NSUMS (3 * CATS + 1)   // 46
#define ITERS 16               // nFloat4 / stride for the fixed problem size
#define DEPTH 2                // LDS ring depth (iteration pairs in flight)
#define PLD 2048               // partials stride in floats (>= NBLOCKS)

typedef float vf4 __attribute__((ext_vector_type(4)));

__device__ __forceinline__ vf4 ntload4(const vf4* p) {
    return __builtin_nontemporal_load(p);
}

// async 16B/lane global->LDS DMA; lds base must be wave-uniform,
// HW writes base + lane*16. Counted by vmcnt.
__device__ __forceinline__ void dma16(const vf4* g, vf4* lds) {
    __builtin_amdgcn_global_load_lds(
        (const __attribute__((address_space(1))) void*)g,
        (__attribute__((address_space(3))) void*)lds,
        16, 0, 0);
}

// softplus(-s) = log(1+exp(-s)) on s in (0,1): degree-4 poly, |err| < 1e-4.
__device__ __forceinline__ float softplus_neg_unit(float s) {
    const float c0 = 0.69314718f, c1 = -0.5f, c2 = 0.125f, c4 = -0.0048853f;
    float s2 = s * s;
    return c0 + fmaf(c1, s, fmaf(c2, s2, c4 * s2 * s2));
}

__device__ __forceinline__ void accum_elem(float x, float l,
                                           float& ssig, float& spos, float& snp,
                                           float& scel) {
    float e   = __expf(-x);                       // transcendental 1
    float sig = __builtin_amdgcn_rcpf(1.0f + e);  // transcendental 2
    ssig += sig;
    spos = fmaf(sig, l, spos);
    snp  += l;
    scel += softplus_neg_unit(sig);
}

__global__ __launch_bounds__(NTHREADS, 8) void mauch_main(
    const float* __restrict__ outp, const float* __restrict__ labp,
    float* __restrict__ ws, int nFloat4, int mode)
{
    const int t = blockIdx.x * blockDim.x + threadIdx.x;
    const int stride = gridDim.x * blockDim.x;   // stride*4 % 15 == 0
    const int lane = threadIdx.x & 63;
    const int wv   = threadIdx.x >> 6;

    float ssig[4] = {0.f, 0.f, 0.f, 0.f};
    float spos[4] = {0.f, 0.f, 0.f, 0.f};
    float snp[4]  = {0.f, 0.f, 0.f, 0.f};
    float scel = 0.f;

    const vf4* o4 = (const vf4*)outp;
    const vf4* l4 = (const vf4*)labp;

    // per-wave private double-buffered staging: [wave][slot][o/l][lane]
    __shared__ vf4 stage[NTHREADS / 64][DEPTH][2][64];

    if (nFloat4 == ITERS * stride) {
        // fixed-size fast path: DMA->LDS ring, wave-private (no barriers)
#pragma unroll
        for (int p = 0; p < DEPTH; ++p) {
            dma16(o4 + t + p * stride, &stage[wv][p][0][0]);
            dma16(l4 + t + p * stride, &stage[wv][p][1][0]);
        }
#pragma unroll
        for (int i = 0; i < ITERS; ++i) {
            const int s = i % DEPTH;
            // wait for the oldest pair (vmcnt decrements in issue order)
            if (i <= ITERS - DEPTH) asm volatile("s_waitcnt vmcnt(2)" ::: "memory");
            else                    asm volatile("s_waitcnt vmcnt(0)" ::: "memory");
            vf4 ov = stage[wv][s][0][lane];
            vf4 lv = stage[wv][s][1][lane];
            // drain ds_reads before the refill DMA may overwrite the slot
            asm volatile("s_waitcnt lgkmcnt(0)" ::: "memory");
            if (i + DEPTH < ITERS) {
                dma16(o4 + t + (i + DEPTH) * stride, &stage[wv][s][0][0]);
                dma16(l4 + t + (i + DEPTH) * stride, &stage[wv][s][1][0]);
            }
#pragma unroll
            for (int j = 0; j < 4; ++j)
                accum_elem(ov[j], lv[j], ssig[j], spos[j], snp[j], scel);
        }
    } else {
        for (int f = t; f < nFloat4; f += stride) {
            vf4 ov = ntload4(o4 + f);
            vf4 lv = ntload4(l4 + f);
#pragma unroll
            for (int j = 0; j < 4; ++j)
                accum_elem(ov[j], lv[j], ssig[j], spos[j], snp[j], scel);
        }
    }

    // ---- block reduction in LDS ----
    __shared__ float red[NSUMS];
    for (int i = threadIdx.x; i < NSUMS; i += blockDim.x) red[i] = 0.f;
    __syncthreads();

    // element categories for this thread: (4t + j) mod 15, constant across iterations
    int base = (4 * t) % CATS;
#pragma unroll
    for (int j = 0; j < 4; ++j) {
        int c = base + j; if (c >= CATS) c -= CATS;
        atomicAdd(&red[c],            ssig[j]);
        atomicAdd(&red[CATS + c],     spos[j]);
        atomicAdd(&red[2 * CATS + c], snp[j]);
    }
    atomicAdd(&red[3 * CATS], scel);
    __syncthreads();

    if (threadIdx.x < NSUMS) {
        if (mode) ws[threadIdx.x * PLD + blockIdx.x] = red[threadIdx.x];  // no atomics, poison-safe
        else      atomicAdd(&ws[threadIdx.x], red[threadIdx.x]);          // small-ws fallback
    }
}

__global__ __launch_bounds__(1024) void mauch_final(
    const float* __restrict__ ws, float* __restrict__ out,
    float invBC, float rowsB, int mode)
{
    __shared__ float sums[NSUMS];
    const int lane = threadIdx.x & 63;
    const int wv   = threadIdx.x >> 6;   // 16 waves

    if (mode) {
        // one wave per sum slot: coalesced strided read + shuffle reduce
        for (int k = wv; k < NSUMS; k += 16) {
            float v = 0.f;
            for (int b = lane; b < NBLOCKS; b += 64) v += ws[k * PLD + b];
#pragma unroll
            for (int off = 32; off; off >>= 1) v += __shfl_down(v, off, 64);
            if (lane == 0) sums[k] = v;
        }
    } else {
        if (threadIdx.x < NSUMS) sums[threadIdx.x] = ws[threadIdx.x];
    }
    __syncthreads();

    if (threadIdx.x == 0) {
        float sum_term = 0.f, pen_last = 0.f;
        float tot_ssig = 0.f, tot_spos = 0.f;
#pragma unroll
        for (int c = 0; c < CATS; ++c) {
            float ssigc = sums[c];
            float sp    = sums[CATS + c];
            float np    = sums[2 * CATS + c];
            float nn    = rowsB - np;
            float sneg  = ssigc - sp;
            tot_ssig += ssigc;
            tot_spos += sp;
            float mp = (np > 0.f) ? sp   / fmaxf(np, 1.f) : 0.f;
            float mn = (nn > 0.f) ? sneg / fmaxf(nn, 1.f) : 0.f;
            float pen = 1.f - mp + mn;
            sum_term += pen;
            if (c == CATS - 1) pen_last = pen;
        }
        // cel = mean(sp + (1-l)*sig); sum((1-l)*sig) = sum(sig) - sum(sig*l)
        float cel = (sums[3 * CATS] + (tot_ssig - tot_spos)) * invBC;
        out[0] = cel + 0.1f * (sum_term / 15.f);
        out[1] = 0.1f * pen_last;
    }
}

extern "C" void kernel_launch(void* const* d_in, const int* in_sizes, int n_in,
                              void* d_out, int out_size, void* d_ws, size_t ws_size,
                              hipStream_t stream) {
    const float* outp = (const float*)d_in[0];
    const float* labp = (const float*)d_in[1];
    float* out = (float*)d_out;
    float* ws  = (float*)d_ws;

    const int total   = in_sizes[0];          // B * 15
    const int nFloat4 = total / 4;
    const float rowsB = (float)(total / CATS);
    const float invBC = 1.0f / (float)total;

    const size_t needed = (size_t)NSUMS * PLD * sizeof(float);
    const int mode = (ws_size >= needed) ? 1 : 0;
    if (!mode) hipMemsetAsync(ws, 0, NSUMS * sizeof(float), stream);  // only for atomic fallback

    mauch_main<<<NBLOCKS, NTHREADS, 0, stream>>>(outp, labp, ws, nFloat4, mode);
    mauch_final<<<1, 1024, 0, stream>>>(ws, out, invBC, rowsB, mode);
}

// Round 2
// 326.972 us; speedup vs baseline: 1.0679x; 1.0679x over previous
//
#include <hip/hip_runtime.h>

// MAUCHLoss: B=2097152 rows, C=15 categories, f32 inputs.
//
// R9: R8 post-mortem — DMA-ring + __launch_bounds__(256,8) spilled to
// scratch (WRITE_SIZE 110MB on a read-only kernel, VALUBusy 9%) -> 155us.
// Root cause of the ORIGINAL 4.6TB/s plateau re-diagnosed as occupancy
// (4 waves/SIMD at VGPR~112), not in-flight bytes. Fix: shallow PF=2
// register pipeline (~50 VGPR, fits the 64-VGPR/8-wave budget), 8 waves/
// SIMD, 1920 blocks (=15*2^7: category phase stays constant per thread,
// 7.5 blocks/CU = one residency round), ITERS=16. Plain loads (no NT:
// single pass; allows L3 hits on restore-resident input). No inline-asm
// waits — compiler-scheduled. Keep R8's no-atomic partial stores
// (poison-safe, no ws memset dispatch).
//
// ws layout (mode=1): ws[k*PLD + block], k in [0,46): 0..14 sum(sig),
// 15..29 sum(sig*label), 30..44 sum(label), 45 sum(softplus(-sig)).

#define CATS 15
#define NBLOCKS 1920  // 1920*256*4 = 1,966,080 = 15*131072 -> phase constant
#define NTHREADS 256
#define NSUMS (3 * CATS + 1)   // 46
#define ITERS 16               // nFloat4 / stride for the fixed problem size
#define PF 2                   // shallow pipeline: 16 buffer VGPRs
#define PLD 2048               // partials stride in floats (>= NBLOCKS)

typedef float vf4 __attribute__((ext_vector_type(4)));

// softplus(-s) = log(1+exp(-s)) on s in (0,1): degree-4 poly, |err| < 1e-4.
__device__ __forceinline__ float softplus_neg_unit(float s) {
    const float c0 = 0.69314718f, c1 = -0.5f, c2 = 0.125f, c4 = -0.0048853f;
    float s2 = s * s;
    return c0 + fmaf(c1, s, fmaf(c2, s2, c4 * s2 * s2));
}

__device__ __forceinline__ void accum_elem(float x, float l,
                                           float& ssig, float& spos, float& snp,
                                           float& scel) {
    float e   = __expf(-x);                       // transcendental 1
    float sig = __builtin_amdgcn_rcpf(1.0f + e);  // transcendental 2
    ssig += sig;
    spos = fmaf(sig, l, spos);
    snp  += l;
    scel += softplus_neg_unit(sig);
}

__global__ __launch_bounds__(NTHREADS, 8) void mauch_main(
    const float* __restrict__ outp, const float* __restrict__ labp,
    float* __restrict__ ws, int nFloat4, int mode)
{
    const int t = blockIdx.x * blockDim.x + threadIdx.x;
    const int stride = gridDim.x * blockDim.x;   // stride*4 % 15 == 0

    float ssig[4] = {0.f, 0.f, 0.f, 0.f};
    float spos[4] = {0.f, 0.f, 0.f, 0.f};
    float snp[4]  = {0.f, 0.f, 0.f, 0.f};
    float scel = 0.f;

    const vf4* o4 = (const vf4*)outp;
    const vf4* l4 = (const vf4*)labp;

    if (nFloat4 == ITERS * stride) {
        // fixed-size fast path: shallow PF-deep register pipeline
        vf4 ob[PF], lb[PF];
#pragma unroll
        for (int p = 0; p < PF; ++p) {
            ob[p] = o4[t + p * stride];
            lb[p] = l4[t + p * stride];
        }
#pragma unroll
        for (int i = 0; i < ITERS; ++i) {
            vf4 ov = ob[i % PF];
            vf4 lv = lb[i % PF];
            if (i + PF < ITERS) {
                ob[i % PF] = o4[t + (i + PF) * stride];
                lb[i % PF] = l4[t + (i + PF) * stride];
            }
#pragma unroll
            for (int j = 0; j < 4; ++j)
                accum_elem(ov[j], lv[j], ssig[j], spos[j], snp[j], scel);
        }
    } else {
        for (int f = t; f < nFloat4; f += stride) {
            vf4 ov = o4[f];
            vf4 lv = l4[f];
#pragma unroll
            for (int j = 0; j < 4; ++j)
                accum_elem(ov[j], lv[j], ssig[j], spos[j], snp[j], scel);
        }
    }

    // ---- block reduction in LDS ----
    __shared__ float red[NSUMS];
    for (int i = threadIdx.x; i < NSUMS; i += blockDim.x) red[i] = 0.f;
    __syncthreads();

    // element categories for this thread: (4t + j) mod 15, constant across iterations
    int base = (4 * t) % CATS;
#pragma unroll
    for (int j = 0; j < 4; ++j) {
        int c = base + j; if (c >= CATS) c -= CATS;
        atomicAdd(&red[c],            ssig[j]);
        atomicAdd(&red[CATS + c],     spos[j]);
        atomicAdd(&red[2 * CATS + c], snp[j]);
    }
    atomicAdd(&red[3 * CATS], scel);
    __syncthreads();

    if (threadIdx.x < NSUMS) {
        if (mode) ws[threadIdx.x * PLD + blockIdx.x] = red[threadIdx.x];  // no atomics, poison-safe
        else      atomicAdd(&ws[threadIdx.x], red[threadIdx.x]);          // small-ws fallback
    }
}

__global__ __launch_bounds__(1024) void mauch_final(
    const float* __restrict__ ws, float* __restrict__ out,
    float invBC, float rowsB, int mode)
{
    __shared__ float sums[NSUMS];
    const int lane = threadIdx.x & 63;
    const int wv   = threadIdx.x >> 6;   // 16 waves

    if (mode) {
        // one wave per sum slot: coalesced strided read + shuffle reduce
        for (int k = wv; k < NSUMS; k += 16) {
            float v = 0.f;
            for (int b = lane; b < NBLOCKS; b += 64) v += ws[k * PLD + b];
#pragma unroll
            for (int off = 32; off; off >>= 1) v += __shfl_down(v, off, 64);
            if (lane == 0) sums[k] = v;
        }
    } else {
        if (threadIdx.x < NSUMS) sums[threadIdx.x] = ws[threadIdx.x];
    }
    __syncthreads();

    if (threadIdx.x == 0) {
        float sum_term = 0.f, pen_last = 0.f;
        float tot_ssig = 0.f, tot_spos = 0.f;
#pragma unroll
        for (int c = 0; c < CATS; ++c) {
            float ssigc = sums[c];
            float sp    = sums[CATS + c];
            float np    = sums[2 * CATS + c];
            float nn    = rowsB - np;
            float sneg  = ssigc - sp;
            tot_ssig += ssigc;
            tot_spos += sp;
            float mp = (np > 0.f) ? sp   / fmaxf(np, 1.f) : 0.f;
            float mn = (nn > 0.f) ? sneg / fmaxf(nn, 1.f) : 0.f;
            float pen = 1.f - mp + mn;
            sum_term += pen;
            if (c == CATS - 1) pen_last = pen;
        }
        // cel = mean(sp + (1-l)*sig); sum((1-l)*sig) = sum(sig) - sum(sig*l)
        float cel = (sums[3 * CATS] + (tot_ssig - tot_spos)) * invBC;
        out[0] = cel + 0.1f * (sum_term / 15.f);
        out[1] = 0.1f * pen_last;
    }
}

extern "C" void kernel_launch(void* const* d_in, const int* in_sizes, int n_in,
                              void* d_out, int out_size, void* d_ws, size_t ws_size,
                              hipStream_t stream) {
    const float* outp = (const float*)d_in[0];
    const float* labp = (const float*)d_in[1];
    float* out = (float*)d_out;
    float* ws  = (float*)d_ws;

    const int total   = in_sizes[0];          // B * 15
    const int nFloat4 = total / 4;
    const float rowsB = (float)(total / CATS);
    const float invBC = 1.0f / (float)total;

    const size_t needed = (size_t)NSUMS * PLD * sizeof(float);
    const int mode = (ws_size >= needed) ? 1 : 0;
    if (!mode) hipMemsetAsync(ws, 0, NSUMS * sizeof(float), stream);  // only for atomic fallback

    mauch_main<<<NBLOCKS, NTHREADS, 0, stream>>>(outp, labp, ws, nFloat4, mode);
    mauch_final<<<1, 1024, 0, stream>>>(ws, out, invBC, rowsB, mode);
}

// Round 3
// 302.253 us; speedup vs baseline: 1.1552x; 1.0818x over previous
//
#include <hip/hip_runtime.h>

// MAUCHLoss: B=2097152 rows, C=15 categories, f32 inputs.
//
// R10: R8/R9 post-mortem — the regression signature (WRITE_SIZE 81-110MB
// on a read-only kernel, VALUBusy ~10%) appeared exactly when
// __launch_bounds__(256,8) was added while the ITERS=16 loop was fully
// unrolled: the scheduler hoists up to 32 independent loads, pressure
// blows past the 64-VGPR cap, and the allocator spills the pipeline to
// scratch -> every iteration pays a scratch round-trip. R7 (no bound,
// 112 VGPR, 4 waves/SIMD) did not spill and ran 55us.
// Fix: keep the 8 waves/SIMD target but limit the scheduler's window:
// plain loop with #pragma unroll 4 (max 8 loads in flight, ~50 VGPR
// live -> no spill). Latency is covered by TLP (8 waves/SIMD), the way
// the measured 82-86%-BW streaming kernels do it, not by a deep
// per-wave pipeline. Keep: 1920 blocks (=15*2^7, category phase
// constant per thread), no-atomic per-block partial stores, no memset.
//
// ws layout (mode=1): ws[k*PLD + block], k in [0,46): 0..14 sum(sig),
// 15..29 sum(sig*label), 30..44 sum(label), 45 sum(softplus(-sig)).

#define CATS 15
#define NBLOCKS 1920  // 1920*256*4 = 1,966,080 = 15*131072 -> phase constant
#define NTHREADS 256
#define NSUMS (3 * CATS + 1)   // 46
#define ITERS 16               // nFloat4 / stride for the fixed problem size
#define PLD 2048               // partials stride in floats (>= NBLOCKS)

typedef float vf4 __attribute__((ext_vector_type(4)));

// softplus(-s) = log(1+exp(-s)) on s in (0,1): degree-4 poly, |err| < 1e-4.
__device__ __forceinline__ float softplus_neg_unit(float s) {
    const float c0 = 0.69314718f, c1 = -0.5f, c2 = 0.125f, c4 = -0.0048853f;
    float s2 = s * s;
    return c0 + fmaf(c1, s, fmaf(c2, s2, c4 * s2 * s2));
}

__device__ __forceinline__ void accum_elem(float x, float l,
                                           float& ssig, float& spos, float& snp,
                                           float& scel) {
    float e   = __expf(-x);                       // transcendental 1
    float sig = __builtin_amdgcn_rcpf(1.0f + e);  // transcendental 2
    ssig += sig;
    spos = fmaf(sig, l, spos);
    snp  += l;
    scel += softplus_neg_unit(sig);
}

__global__ __launch_bounds__(NTHREADS, 8) void mauch_main(
    const float* __restrict__ outp, const float* __restrict__ labp,
    float* __restrict__ ws, int nFloat4, int mode)
{
    const int t = blockIdx.x * blockDim.x + threadIdx.x;
    const int stride = gridDim.x * blockDim.x;   // stride*4 % 15 == 0

    float ssig[4] = {0.f, 0.f, 0.f, 0.f};
    float spos[4] = {0.f, 0.f, 0.f, 0.f};
    float snp[4]  = {0.f, 0.f, 0.f, 0.f};
    float scel = 0.f;

    const vf4* o4 = (const vf4*)outp;
    const vf4* l4 = (const vf4*)labp;

    if (nFloat4 == ITERS * stride) {
        // fixed trip count; unroll 4 only: <=8 loads in flight per wave,
        // live pressure stays under the 64-VGPR / 8-wave budget (no spill).
#pragma unroll 4
        for (int i = 0; i < ITERS; ++i) {
            vf4 ov = o4[t + i * stride];
            vf4 lv = l4[t + i * stride];
#pragma unroll
            for (int j = 0; j < 4; ++j)
                accum_elem(ov[j], lv[j], ssig[j], spos[j], snp[j], scel);
        }
    } else {
#pragma unroll 1
        for (int f = t; f < nFloat4; f += stride) {
            vf4 ov = o4[f];
            vf4 lv = l4[f];
#pragma unroll
            for (int j = 0; j < 4; ++j)
                accum_elem(ov[j], lv[j], ssig[j], spos[j], snp[j], scel);
        }
    }

    // ---- block reduction in LDS ----
    __shared__ float red[NSUMS];
    for (int i = threadIdx.x; i < NSUMS; i += blockDim.x) red[i] = 0.f;
    __syncthreads();

    // element categories for this thread: (4t + j) mod 15, constant across iterations
    int base = (4 * t) % CATS;
#pragma unroll
    for (int j = 0; j < 4; ++j) {
        int c = base + j; if (c >= CATS) c -= CATS;
        atomicAdd(&red[c],            ssig[j]);
        atomicAdd(&red[CATS + c],     spos[j]);
        atomicAdd(&red[2 * CATS + c], snp[j]);
    }
    atomicAdd(&red[3 * CATS], scel);
    __syncthreads();

    if (threadIdx.x < NSUMS) {
        if (mode) ws[threadIdx.x * PLD + blockIdx.x] = red[threadIdx.x];  // no atomics, poison-safe
        else      atomicAdd(&ws[threadIdx.x], red[threadIdx.x]);          // small-ws fallback
    }
}

__global__ __launch_bounds__(1024) void mauch_final(
    const float* __restrict__ ws, float* __restrict__ out,
    float invBC, float rowsB, int mode)
{
    __shared__ float sums[NSUMS];
    const int lane = threadIdx.x & 63;
    const int wv   = threadIdx.x >> 6;   // 16 waves

    if (mode) {
        // one wave per sum slot: coalesced strided read + shuffle reduce
        for (int k = wv; k < NSUMS; k += 16) {
            float v = 0.f;
            for (int b = lane; b < NBLOCKS; b += 64) v += ws[k * PLD + b];
#pragma unroll
            for (int off = 32; off; off >>= 1) v += __shfl_down(v, off, 64);
            if (lane == 0) sums[k] = v;
        }
    } else {
        if (threadIdx.x < NSUMS) sums[threadIdx.x] = ws[threadIdx.x];
    }
    __syncthreads();

    if (threadIdx.x == 0) {
        float sum_term = 0.f, pen_last = 0.f;
        float tot_ssig = 0.f, tot_spos = 0.f;
#pragma unroll
        for (int c = 0; c < CATS; ++c) {
            float ssigc = sums[c];
            float sp    = sums[CATS + c];
            float np    = sums[2 * CATS + c];
            float nn    = rowsB - np;
            float sneg  = ssigc - sp;
            tot_ssig += ssigc;
            tot_spos += sp;
            float mp = (np > 0.f) ? sp   / fmaxf(np, 1.f) : 0.f;
            float mn = (nn > 0.f) ? sneg / fmaxf(nn, 1.f) : 0.f;
            float pen = 1.f - mp + mn;
            sum_term += pen;
            if (c == CATS - 1) pen_last = pen;
        }
        // cel = mean(sp + (1-l)*sig); sum((1-l)*sig) = sum(sig) - sum(sig*l)
        float cel = (sums[3 * CATS] + (tot_ssig - tot_spos)) * invBC;
        out[0] = cel + 0.1f * (sum_term / 15.f);
        out[1] = 0.1f * pen_last;
    }
}

extern "C" void kernel_launch(void* const* d_in, const int* in_sizes, int n_in,
                              void* d_out, int out_size, void* d_ws, size_t ws_size,
                              hipStream_t stream) {
    const float* outp = (const float*)d_in[0];
    const float* labp = (const float*)d_in[1];
    float* out = (float*)d_out;
    float* ws  = (float*)d_ws;

    const int total   = in_sizes[0];          // B * 15
    const int nFloat4 = total / 4;
    const float rowsB = (float)(total / CATS);
    const float invBC = 1.0f / (float)total;

    const size_t needed = (size_t)NSUMS * PLD * sizeof(float);
    const int mode = (ws_size >= needed) ? 1 : 0;
    if (!mode) hipMemsetAsync(ws, 0, NSUMS * sizeof(float), stream);  // only for atomic fallback

    mauch_main<<<NBLOCKS, NTHREADS, 0, stream>>>(outp, labp, ws, nFloat4, mode);
    mauch_final<<<1, 1024, 0, stream>>>(ws, out, invBC, rowsB, mode);
}